// Round 18
// baseline (45.509 us; speedup 1.0000x reference)
//
#include <hip/hip_runtime.h>
#include <hip/hip_bf16.h>

#define NN 512
#define DD 128

typedef __bf16 bf16x8 __attribute__((ext_vector_type(8)));
typedef float f32x4 __attribute__((ext_vector_type(4)));

static __device__ __forceinline__ f32x4 mfma16(bf16x8 a, bf16x8 b, f32x4 c) {
  return __builtin_amdgcn_mfma_f32_16x16x32_bf16(a, b, c, 0, 0, 0);
}

// -------- phase 0 (fused): w1t transpose + hjp + cnt --------
__global__ void k_pre(const float* __restrict__ h,
                      const float* __restrict__ msg_w1,
                      const float* __restrict__ msg_b1,
                      const int* __restrict__ emask,
                      __bf16* __restrict__ w1t, float* __restrict__ hjp,
                      float* __restrict__ cnt) {
  __shared__ float hr[128];
  __shared__ int csum;
  int j = blockIdx.x, t = threadIdx.x;
  if (t == 0) csum = 0;
  hr[t] = h[j * 128 + t];
  __syncthreads();
  float a0 = msg_b1[t], a1 = 0.f;
  #pragma unroll 16
  for (int k = 0; k < 128; k += 2) {
    a0 += hr[k] * msg_w1[k * 128 + t];
    a1 += hr[k + 1] * msg_w1[(k + 1) * 128 + t];
  }
  hjp[j * 128 + t] = a0 + a1;
  if (t < 32) {
    int tt = j * 32 + t;
    int e = tt >> 7, k = tt & 127;
    w1t[e * 128 + k] = (__bf16)msg_w1[(128 + k) * 128 + e];
  }
  int s = 0;
  #pragma unroll
  for (int r = 0; r < 4; r++) s += emask[(t * 4 + r) * NN + j] ? 1 : 0;
  #pragma unroll
  for (int off = 32; off > 0; off >>= 1) s += __shfl_down(s, off, 64);
  if ((t & 63) == 0) atomicAdd(&csum, s);
  __syncthreads();
  if (t == 0) cnt[j] = (float)csum;
}

// ---------------- phase 1: T[i][e] = sum_j mask[j,i]*silu(pre[j,i,e]) ----
// R15 dataflow restored exactly (best: 43.2us): depth-4 pipeline, 2 tile
// buffers, hjl in LDS, COMPUTE = zero-init C -> MFMA chain -> hv read
// AFTER chain + VALU add. R17's C-init-from-LDS serialized the hjl
// lgkmcnt ahead of the MFMA chain head (+2us) -- reverted. Kept from R17
// (mechanistically positive): prologue bitmasks (zero per-step mk
// ds_reads; LDS pipe is the measured binder) and 128x512 k_update.
// (256,2) = cap 256, the only spill-free cap (R1-R10 allocator law).
#define CVT(bf, xa, xb) { \
  bf[0] = (__bf16)xa[0]; bf[1] = (__bf16)xa[1]; \
  bf[2] = (__bf16)xa[2]; bf[3] = (__bf16)xa[3]; \
  bf[4] = (__bf16)xb[0]; bf[5] = (__bf16)xb[1]; \
  bf[6] = (__bf16)xb[2]; bf[7] = (__bf16)xb[3]; }

__global__ __launch_bounds__(256, 2) void k_main(
    const float* __restrict__ rel, const int* __restrict__ emask,
    const float* __restrict__ hjp, const __bf16* __restrict__ w1t_g,
    float* __restrict__ partial) {
  __shared__ __align__(16) __bf16 tile[2 * 16 * 136];
  __shared__ float mk[256];
  __shared__ __align__(16) float hjl[16 * 128];
  const int tid = threadIdx.x;
  const int wave = tid >> 6;
  const int lane = tid & 63;
  const int l15 = lane & 15;
  const int q = lane >> 4;

  const int it = blockIdx.x >> 5;    // 0..31 : 16-row i-tile
  const int jc = blockIdx.x & 31;    // 0..31 : 16-col j-chunk
  const int irow = it * 16;
  const int jbase = jc * 16;

  // mask table + hjp slice staging
  mk[tid] = emask[(size_t)(jbase + (tid >> 4)) * NN + irow + (tid & 15)] ? 1.f : 0.f;
  {
    int r2 = tid >> 4, c8 = (tid & 15) * 8;
    const float* hsrc = hjp + (size_t)(jbase + r2) * DD + c8;
    *(f32x4*)(hjl + r2 * 128 + c8) = *(const f32x4*)hsrc;
    *(f32x4*)(hjl + r2 * 128 + c8 + 4) = *(const f32x4*)(hsrc + 4);
  }

  // wave-private w1 fragments for e-slice [32w, 32w+32)
  bf16x8 aw00, aw01, aw02, aw03, aw10, aw11, aw12, aw13;
  {
    const __bf16* b0 = w1t_g + (wave * 32 + l15) * 128 + q * 8;
    aw00 = *(const bf16x8*)(b0);
    aw01 = *(const bf16x8*)(b0 + 32);
    aw02 = *(const bf16x8*)(b0 + 64);
    aw03 = *(const bf16x8*)(b0 + 96);
    const __bf16* b1 = b0 + 16 * 128;
    aw10 = *(const bf16x8*)(b1);
    aw11 = *(const bf16x8*)(b1 + 32);
    aw12 = *(const bf16x8*)(b1 + 64);
    aw13 = *(const bf16x8*)(b1 + 96);
  }

  // t0[r] = T[i=l15][e=32w+q*4+r], t1 = +16
  f32x4 t0 = {0.f, 0.f, 0.f, 0.f}, t1 = t0;

  // staging role: thread covers row srow, 8-float chunk schunk
  const int srow = tid >> 4;
  const int schunk = tid & 15;
  const float* sb = rel + ((size_t)jbase * NN + irow + srow) * DD + schunk * 8;
  __bf16* sd = tile + srow * 136 + schunk * 8;

  __syncthreads();   // mk + hjl visible

  // bitmasks: stage-predicate (per srow) and compute-mask (per l15);
  // mk LDS is dead in the hot loop afterwards
  unsigned msS = 0, msC = 0;
  #pragma unroll
  for (int jr = 0; jr < 16; jr++) {
    msS |= (mk[jr * 16 + srow] != 0.f) ? (1u << jr) : 0u;
    msC |= (mk[jr * 16 + l15] != 0.f) ? (1u << jr) : 0u;
  }

  // prologue: zero all 4 staging sets; stage row0 -> tile[0];
  // load rows 1..4 -> A..D (predicated; stale contents finite; ms=0 masks).
  f32x4 xa0 = {0.f, 0.f, 0.f, 0.f}, xb0 = xa0;
  f32x4 xa1 = xa0, xb1 = xa0;
  f32x4 xa2 = xa0, xb2 = xa0;
  f32x4 xa3 = xa0, xb3 = xa0;
  {
    f32x4 ra = xa0, rb = xa0;
    if (msS & 1u) { ra = *(const f32x4*)sb; rb = *(const f32x4*)(sb + 4); }
    bf16x8 pub;
    CVT(pub, ra, rb)
    *(bf16x8*)sd = pub;
    if (msS & 2u) {
      const float* s = sb + (size_t)NN * DD;
      xa0 = *(const f32x4*)s; xb0 = *(const f32x4*)(s + 4);
    }
    if (msS & 4u) {
      const float* s = sb + 2 * (size_t)NN * DD;
      xa1 = *(const f32x4*)s; xb1 = *(const f32x4*)(s + 4);
    }
    if (msS & 8u) {
      const float* s = sb + 3 * (size_t)NN * DD;
      xa2 = *(const f32x4*)s; xb2 = *(const f32x4*)(s + 4);
    }
    if (msS & 16u) {
      const float* s = sb + 4 * (size_t)NN * DD;
      xa3 = *(const f32x4*)s; xb3 = *(const f32x4*)(s + 4);
    }
  }

  // COMPUTE: R15 dataflow -- zero-init C, MFMA chain, hv read AFTER the
  // chain from LDS hjl, VALU add + silu + masked accumulate.
  #define COMPUTE(JROW) { \
    const float ms = ((msC >> (JROW)) & 1) ? 1.f : 0.f; \
    const __bf16* tp = tile + (((JROW) & 1) ? 2176 : 0) + l15 * 136 + q * 8; \
    bf16x8 bf0 = *(const bf16x8*)(tp); \
    bf16x8 bf1 = *(const bf16x8*)(tp + 32); \
    bf16x8 bf2 = *(const bf16x8*)(tp + 64); \
    bf16x8 bf3 = *(const bf16x8*)(tp + 96); \
    f32x4 p0 = {0.f, 0.f, 0.f, 0.f}, p1 = p0; \
    p0 = mfma16(aw00, bf0, p0); p1 = mfma16(aw10, bf0, p1); \
    p0 = mfma16(aw01, bf1, p0); p1 = mfma16(aw11, bf1, p1); \
    p0 = mfma16(aw02, bf2, p0); p1 = mfma16(aw12, bf2, p1); \
    p0 = mfma16(aw03, bf3, p0); p1 = mfma16(aw13, bf3, p1); \
    const float* hj = hjl + (JROW) * 128 + wave * 32 + q * 4; \
    f32x4 hv0 = *(const f32x4*)(hj); \
    f32x4 hv1 = *(const f32x4*)(hj + 16); \
    _Pragma("unroll") \
    for (int r = 0; r < 4; r++) { \
      float v0 = p0[r] + hv0[r]; \
      float v1 = p1[r] + hv1[r]; \
      t0[r] += ms * v0 * __builtin_amdgcn_rcpf(1.f + __expf(-v0)); \
      t1[r] += ms * v1 * __builtin_amdgcn_rcpf(1.f + __expf(-v1)); \
    } }

  // STEP(JR, set): barrier; publish row JR+1 from set; load row JR+5 -> set;
  // compute row JR. Set rotation: step JR uses set JR&3 (reused at JR+4,
  // holding row JR+5 = (JR+4)+1). Rest = 4 steps per load (~1000cy >= HBM).
  #define STEP(JR, XA, XB) { \
    __syncthreads(); \
    if ((JR) + 1 < 16) { \
      bf16x8 pub; \
      CVT(pub, XA, XB) \
      *(bf16x8*)(sd + ((((JR) + 1) & 1) ? 2176 : 0)) = pub; \
    } \
    if ((JR) + 5 < 16) { \
      if ((msS >> ((JR) + 5)) & 1) { \
        const float* s = sb + (size_t)((JR) + 5) * NN * DD; \
        XA = *(const f32x4*)s; XB = *(const f32x4*)(s + 4); \
      } \
    } \
    COMPUTE(JR) }

  #pragma unroll 1
  for (int jj = 0; jj < 16; jj += 4) {
    STEP(jj,     xa0, xb0)
    STEP(jj + 1, xa1, xb1)
    STEP(jj + 2, xa2, xb2)
    STEP(jj + 3, xa3, xb3)
  }
  #undef STEP
  #undef COMPUTE

  // direct per-wave e-slice write (no cross-wave reduction needed)
  float* pp = partial + ((size_t)jc * NN + irow + l15) * DD + wave * 32 + q * 4;
  *(f32x4*)pp = t0;
  *(f32x4*)(pp + 16) = t1;
}

// ------- phase 2: T-reduce + GEMM2(f32) + update MLP + LayerNorm -------
// 128 blocks x 512 threads; group g handles row i = blk*4+g. Weight
// columns identical across groups -> L1 serves 3 of 4; L2 traffic /4.
__global__ void k_update(const float* __restrict__ h, const float* __restrict__ partial,
                         const float* __restrict__ w2, const float* __restrict__ b2,
                         const float* __restrict__ cnt,
                         const float* __restrict__ uw1, const float* __restrict__ ub1,
                         const float* __restrict__ uw2, const float* __restrict__ ub2,
                         const float* __restrict__ g, const float* __restrict__ bb,
                         float* __restrict__ out) {
  __shared__ float Trow[4][128];
  __shared__ float uin[4][256];
  __shared__ float zl[4][128];
  __shared__ float ss[4][4];
  int gi = threadIdx.x >> 7, t = threadIdx.x & 127;
  int i = blockIdx.x * 4 + gi;
  float hv = h[i * 128 + t];
  float ts = 0.f;
  #pragma unroll
  for (int c = 0; c < 32; c++) ts += partial[((size_t)c * NN + i) * DD + t];
  Trow[gi][t] = ts;
  __syncthreads();
  float a0 = cnt[i] * b2[t], a1 = 0.f;
  #pragma unroll 16
  for (int e = 0; e < 128; e += 2) {
    a0 += Trow[gi][e] * w2[e * 128 + t];
    a1 += Trow[gi][e + 1] * w2[(e + 1) * 128 + t];
  }
  uin[gi][t] = hv;
  uin[gi][128 + t] = a0 + a1;
  __syncthreads();
  float z0 = ub1[t], z1 = 0.f, z2 = 0.f, z3 = 0.f;
  #pragma unroll 16
  for (int k = 0; k < 256; k += 4) {
    z0 += uin[gi][k] * uw1[k * 128 + t];
    z1 += uin[gi][k + 1] * uw1[(k + 1) * 128 + t];
    z2 += uin[gi][k + 2] * uw1[(k + 2) * 128 + t];
    z3 += uin[gi][k + 3] * uw1[(k + 3) * 128 + t];
  }
  float z = (z0 + z1) + (z2 + z3);
  z = z / (1.f + __expf(-z));
  zl[gi][t] = z;
  __syncthreads();
  float d0 = ub2[t], d1 = 0.f;
  #pragma unroll 16
  for (int k = 0; k < 128; k += 2) {
    d0 += zl[gi][k] * uw2[k * 128 + t];
    d1 += zl[gi][k + 1] * uw2[(k + 1) * 128 + t];
  }
  float x = hv + d0 + d1;
  float s1 = x, s2 = x * x;
  #pragma unroll
  for (int off = 32; off > 0; off >>= 1) {
    s1 += __shfl_down(s1, off, 64);
    s2 += __shfl_down(s2, off, 64);
  }
  if ((t & 63) == 0) { ss[gi][(t >> 6) * 2] = s1; ss[gi][(t >> 6) * 2 + 1] = s2; }
  __syncthreads();
  s1 = ss[gi][0] + ss[gi][2];
  s2 = ss[gi][1] + ss[gi][3];
  float mu = s1 * (1.f / 128.f);
  float var = s2 * (1.f / 128.f) - mu * mu;
  out[i * 128 + t] = (x - mu) * rsqrtf(var + 1e-5f) * g[t] + bb[t];
}

extern "C" void kernel_launch(void* const* d_in, const int* in_sizes, int n_in,
                              void* d_out, int out_size, void* d_ws, size_t ws_size,
                              hipStream_t stream) {
  const float* h      = (const float*)d_in[0];
  const float* rel    = (const float*)d_in[1];
  const int*   emask  = (const int*)d_in[2];
  const float* msg_w1 = (const float*)d_in[3];
  const float* msg_b1 = (const float*)d_in[4];
  const float* msg_w2 = (const float*)d_in[5];
  const float* msg_b2 = (const float*)d_in[6];
  const float* upd_w1 = (const float*)d_in[7];
  const float* upd_b1 = (const float*)d_in[8];
  const float* upd_w2 = (const float*)d_in[9];
  const float* upd_b2 = (const float*)d_in[10];
  const float* ln_g   = (const float*)d_in[11];
  const float* ln_b   = (const float*)d_in[12];
  float* out = (float*)d_out;

  char* ws = (char*)d_ws;
  float*  hjp     = (float*)ws;                        // 262144 B
  __bf16* w1t     = (__bf16*)(ws + 262144);            // 32768 B
  float*  cnt     = (float*)(ws + 262144 + 32768);     // 2048 B
  float*  partial = (float*)(ws + 262144 + 36864);     // 32*512*128*4 = 8 MiB

  k_pre<<<512, 128, 0, stream>>>(h, msg_w1, msg_b1, emask, w1t, hjp, cnt);
  k_main<<<1024, 256, 0, stream>>>(rel, emask, hjp, w1t, partial);
  k_update<<<128, 512, 0, stream>>>(h, partial, msg_w2, msg_b2, cnt,
                                    upd_w1, upd_b1, upd_w2, upd_b2,
                                    ln_g, ln_b, out);
}

// Round 19
// 43.137 us; speedup vs baseline: 1.0550x; 1.0550x over previous
//
#include <hip/hip_runtime.h>
#include <hip/hip_bf16.h>

#define NN 512
#define DD 128

typedef __bf16 bf16x8 __attribute__((ext_vector_type(8)));
typedef float f32x4 __attribute__((ext_vector_type(4)));

static __device__ __forceinline__ f32x4 mfma16(bf16x8 a, bf16x8 b, f32x4 c) {
  return __builtin_amdgcn_mfma_f32_16x16x32_bf16(a, b, c, 0, 0, 0);
}

// -------- phase 0 (fused): w1t transpose + hjp + cnt --------
__global__ void k_pre(const float* __restrict__ h,
                      const float* __restrict__ msg_w1,
                      const float* __restrict__ msg_b1,
                      const int* __restrict__ emask,
                      __bf16* __restrict__ w1t, float* __restrict__ hjp,
                      float* __restrict__ cnt) {
  __shared__ float hr[128];
  __shared__ int csum;
  int j = blockIdx.x, t = threadIdx.x;
  if (t == 0) csum = 0;
  hr[t] = h[j * 128 + t];
  __syncthreads();
  float a0 = msg_b1[t], a1 = 0.f;
  #pragma unroll 16
  for (int k = 0; k < 128; k += 2) {
    a0 += hr[k] * msg_w1[k * 128 + t];
    a1 += hr[k + 1] * msg_w1[(k + 1) * 128 + t];
  }
  hjp[j * 128 + t] = a0 + a1;
  // w1t[e][k] = msg_w1[128+k][e] : 32 elements per block
  if (t < 32) {
    int tt = j * 32 + t;
    int e = tt >> 7, k = tt & 127;
    w1t[e * 128 + k] = (__bf16)msg_w1[(128 + k) * 128 + e];
  }
  // cnt[j] = sum_r emask[r][j]
  int s = 0;
  #pragma unroll
  for (int r = 0; r < 4; r++) s += emask[(t * 4 + r) * NN + j] ? 1 : 0;
  #pragma unroll
  for (int off = 32; off > 0; off >>= 1) s += __shfl_down(s, off, 64);
  if ((t & 63) == 0) atomicAdd(&csum, s);
  __syncthreads();
  if (t == 0) cnt[j] = (float)csum;
}

// ---------------- phase 1: T[i][e] = sum_j mask[j,i]*silu(pre[j,i,e]) ----
// EXACT R15 kernel (measured best: 43.2us total). Depth-4 pipeline: four
// static staging sets A-D; step JR uses set JR&3: publish row JR+1 ->
// tile[(JR+1)&1], load row JR+5 -> same set. Rest = 4 steps (~1000cy).
// hjp block-slice (16 rows, 8KB) staged to LDS once; hv read AFTER the
// MFMA chain + VALU add (R16/R17 C-init variants regressed or were
// neutral). Per-step mk LDS reads (prologue-bitmask variant was part of
// the R17/R18 +2us bundle). k_update 512x128 (128-block variant idles
// half the CUs). Publishes unconditional-data (regs prologue-zeroed;
// stale = finite; ms=0 masks exactly -> bit-identical).
// (256,2) = cap 256, the only spill-free cap (R1-R10 allocator law).
#define CVT(bf, xa, xb) { \
  bf[0] = (__bf16)xa[0]; bf[1] = (__bf16)xa[1]; \
  bf[2] = (__bf16)xa[2]; bf[3] = (__bf16)xa[3]; \
  bf[4] = (__bf16)xb[0]; bf[5] = (__bf16)xb[1]; \
  bf[6] = (__bf16)xb[2]; bf[7] = (__bf16)xb[3]; }

__global__ __launch_bounds__(256, 2) void k_main(
    const float* __restrict__ rel, const int* __restrict__ emask,
    const float* __restrict__ hjp, const __bf16* __restrict__ w1t_g,
    float* __restrict__ partial) {
  __shared__ __align__(16) __bf16 tile[2 * 16 * 136];
  __shared__ float mk[256];
  __shared__ __align__(16) float hjl[16 * 128];
  const int tid = threadIdx.x;
  const int wave = tid >> 6;
  const int lane = tid & 63;
  const int l15 = lane & 15;
  const int q = lane >> 4;

  const int it = blockIdx.x >> 5;    // 0..31 : 16-row i-tile
  const int jc = blockIdx.x & 31;    // 0..31 : 16-col j-chunk
  const int irow = it * 16;
  const int jbase = jc * 16;

  // mask table + hjp slice staging
  mk[tid] = emask[(size_t)(jbase + (tid >> 4)) * NN + irow + (tid & 15)] ? 1.f : 0.f;
  {
    int r2 = tid >> 4, c8 = (tid & 15) * 8;
    const float* hsrc = hjp + (size_t)(jbase + r2) * DD + c8;
    *(f32x4*)(hjl + r2 * 128 + c8) = *(const f32x4*)hsrc;
    *(f32x4*)(hjl + r2 * 128 + c8 + 4) = *(const f32x4*)(hsrc + 4);
  }

  // wave-private w1 fragments for e-slice [32w, 32w+32)
  bf16x8 aw00, aw01, aw02, aw03, aw10, aw11, aw12, aw13;
  {
    const __bf16* b0 = w1t_g + (wave * 32 + l15) * 128 + q * 8;
    aw00 = *(const bf16x8*)(b0);
    aw01 = *(const bf16x8*)(b0 + 32);
    aw02 = *(const bf16x8*)(b0 + 64);
    aw03 = *(const bf16x8*)(b0 + 96);
    const __bf16* b1 = b0 + 16 * 128;
    aw10 = *(const bf16x8*)(b1);
    aw11 = *(const bf16x8*)(b1 + 32);
    aw12 = *(const bf16x8*)(b1 + 64);
    aw13 = *(const bf16x8*)(b1 + 96);
  }

  // t0[r] = T[i=l15][e=32w+q*4+r], t1 = +16
  f32x4 t0 = {0.f, 0.f, 0.f, 0.f}, t1 = t0;

  // staging role: thread covers row srow, 8-float chunk schunk
  const int srow = tid >> 4;
  const int schunk = tid & 15;
  const float* sb = rel + ((size_t)jbase * NN + irow + srow) * DD + schunk * 8;
  __bf16* sd = tile + srow * 136 + schunk * 8;

  __syncthreads();   // mk + hjl visible

  // prologue: zero all 4 staging sets; stage row0 -> tile[0];
  // load rows 1..4 -> A..D (predicated; stale contents finite; ms=0 masks).
  f32x4 xa0 = {0.f, 0.f, 0.f, 0.f}, xb0 = xa0;
  f32x4 xa1 = xa0, xb1 = xa0;
  f32x4 xa2 = xa0, xb2 = xa0;
  f32x4 xa3 = xa0, xb3 = xa0;
  {
    f32x4 ra = xa0, rb = xa0;
    if (mk[srow] != 0.f) { ra = *(const f32x4*)sb; rb = *(const f32x4*)(sb + 4); }
    bf16x8 pub;
    CVT(pub, ra, rb)
    *(bf16x8*)sd = pub;
    if (mk[16 + srow] != 0.f) {
      const float* s = sb + (size_t)NN * DD;
      xa0 = *(const f32x4*)s; xb0 = *(const f32x4*)(s + 4);
    }
    if (mk[32 + srow] != 0.f) {
      const float* s = sb + 2 * (size_t)NN * DD;
      xa1 = *(const f32x4*)s; xb1 = *(const f32x4*)(s + 4);
    }
    if (mk[48 + srow] != 0.f) {
      const float* s = sb + 3 * (size_t)NN * DD;
      xa2 = *(const f32x4*)s; xb2 = *(const f32x4*)(s + 4);
    }
    if (mk[64 + srow] != 0.f) {
      const float* s = sb + 4 * (size_t)NN * DD;
      xa3 = *(const f32x4*)s; xb3 = *(const f32x4*)(s + 4);
    }
  }

  #define COMPUTE(JROW) { \
    const float ms = mk[(JROW) * 16 + l15]; \
    const __bf16* tp = tile + (((JROW) & 1) ? 2176 : 0) + l15 * 136 + q * 8; \
    bf16x8 bf0 = *(const bf16x8*)(tp); \
    bf16x8 bf1 = *(const bf16x8*)(tp + 32); \
    bf16x8 bf2 = *(const bf16x8*)(tp + 64); \
    bf16x8 bf3 = *(const bf16x8*)(tp + 96); \
    f32x4 p0 = {0.f, 0.f, 0.f, 0.f}, p1 = p0; \
    p0 = mfma16(aw00, bf0, p0); p1 = mfma16(aw10, bf0, p1); \
    p0 = mfma16(aw01, bf1, p0); p1 = mfma16(aw11, bf1, p1); \
    p0 = mfma16(aw02, bf2, p0); p1 = mfma16(aw12, bf2, p1); \
    p0 = mfma16(aw03, bf3, p0); p1 = mfma16(aw13, bf3, p1); \
    const float* hj = hjl + (JROW) * 128 + wave * 32 + q * 4; \
    f32x4 hv0 = *(const f32x4*)(hj); \
    f32x4 hv1 = *(const f32x4*)(hj + 16); \
    _Pragma("unroll") \
    for (int r = 0; r < 4; r++) { \
      float v0 = p0[r] + hv0[r]; \
      float v1 = p1[r] + hv1[r]; \
      t0[r] += ms * v0 * __builtin_amdgcn_rcpf(1.f + __expf(-v0)); \
      t1[r] += ms * v1 * __builtin_amdgcn_rcpf(1.f + __expf(-v1)); \
    } }

  // STEP(JR, set): barrier; publish row JR+1 from set; load row JR+5 -> set;
  // compute row JR. Set rotation: step JR uses set JR&3 (reused at JR+4,
  // holding row JR+5 = (JR+4)+1). Rest = 4 steps per load.
  #define STEP(JR, XA, XB) { \
    __syncthreads(); \
    if ((JR) + 1 < 16) { \
      bf16x8 pub; \
      CVT(pub, XA, XB) \
      *(bf16x8*)(sd + ((((JR) + 1) & 1) ? 2176 : 0)) = pub; \
    } \
    if ((JR) + 5 < 16) { \
      if (mk[((JR) + 5) * 16 + srow] != 0.f) { \
        const float* s = sb + (size_t)((JR) + 5) * NN * DD; \
        XA = *(const f32x4*)s; XB = *(const f32x4*)(s + 4); \
      } \
    } \
    COMPUTE(JR) }

  #pragma unroll 1
  for (int jj = 0; jj < 16; jj += 4) {
    STEP(jj,     xa0, xb0)
    STEP(jj + 1, xa1, xb1)
    STEP(jj + 2, xa2, xb2)
    STEP(jj + 3, xa3, xb3)
  }
  #undef STEP
  #undef COMPUTE

  // direct per-wave e-slice write (no cross-wave reduction needed)
  float* pp = partial + ((size_t)jc * NN + irow + l15) * DD + wave * 32 + q * 4;
  *(f32x4*)pp = t0;
  *(f32x4*)(pp + 16) = t1;
}

// ------- phase 2: T-reduce + GEMM2(f32) + update MLP + LayerNorm -------
__global__ void k_update(const float* __restrict__ h, const float* __restrict__ partial,
                         const float* __restrict__ w2, const float* __restrict__ b2,
                         const float* __restrict__ cnt,
                         const float* __restrict__ uw1, const float* __restrict__ ub1,
                         const float* __restrict__ uw2, const float* __restrict__ ub2,
                         const float* __restrict__ g, const float* __restrict__ bb,
                         float* __restrict__ out) {
  __shared__ float Trow[128];
  __shared__ float uin[256];
  __shared__ float zl[128];
  __shared__ float ss[4];
  int i = blockIdx.x, t = threadIdx.x;
  float hv = h[i * 128 + t];
  float ts = 0.f;
  #pragma unroll
  for (int c = 0; c < 32; c++) ts += partial[((size_t)c * NN + i) * DD + t];
  Trow[t] = ts;
  __syncthreads();
  float a0 = cnt[i] * b2[t], a1 = 0.f;
  #pragma unroll 16
  for (int e = 0; e < 128; e += 2) {
    a0 += Trow[e] * w2[e * 128 + t];
    a1 += Trow[e + 1] * w2[(e + 1) * 128 + t];
  }
  uin[t] = hv;
  uin[128 + t] = a0 + a1;
  __syncthreads();
  float z0 = ub1[t], z1 = 0.f, z2 = 0.f, z3 = 0.f;
  #pragma unroll 16
  for (int k = 0; k < 256; k += 4) {
    z0 += uin[k] * uw1[k * 128 + t];
    z1 += uin[k + 1] * uw1[(k + 1) * 128 + t];
    z2 += uin[k + 2] * uw1[(k + 2) * 128 + t];
    z3 += uin[k + 3] * uw1[(k + 3) * 128 + t];
  }
  float z = (z0 + z1) + (z2 + z3);
  z = z / (1.f + __expf(-z));
  zl[t] = z;
  __syncthreads();
  float d0 = ub2[t], d1 = 0.f;
  #pragma unroll 16
  for (int k = 0; k < 128; k += 2) {
    d0 += zl[k] * uw2[k * 128 + t];
    d1 += zl[k + 1] * uw2[(k + 1) * 128 + t];
  }
  float x = hv + d0 + d1;
  float s1 = x, s2 = x * x;
  #pragma unroll
  for (int off = 32; off > 0; off >>= 1) {
    s1 += __shfl_down(s1, off, 64);
    s2 += __shfl_down(s2, off, 64);
  }
  if ((t & 63) == 0) { ss[(t >> 6) * 2] = s1; ss[(t >> 6) * 2 + 1] = s2; }
  __syncthreads();
  s1 = ss[0] + ss[2];
  s2 = ss[1] + ss[3];
  float mu = s1 * (1.f / 128.f);
  float var = s2 * (1.f / 128.f) - mu * mu;
  out[i * 128 + t] = (x - mu) * rsqrtf(var + 1e-5f) * g[t] + bb[t];
}

extern "C" void kernel_launch(void* const* d_in, const int* in_sizes, int n_in,
                              void* d_out, int out_size, void* d_ws, size_t ws_size,
                              hipStream_t stream) {
  const float* h      = (const float*)d_in[0];
  const float* rel    = (const float*)d_in[1];
  const int*   emask  = (const int*)d_in[2];
  const float* msg_w1 = (const float*)d_in[3];
  const float* msg_b1 = (const float*)d_in[4];
  const float* msg_w2 = (const float*)d_in[5];
  const float* msg_b2 = (const float*)d_in[6];
  const float* upd_w1 = (const float*)d_in[7];
  const float* upd_b1 = (const float*)d_in[8];
  const float* upd_w2 = (const float*)d_in[9];
  const float* upd_b2 = (const float*)d_in[10];
  const float* ln_g   = (const float*)d_in[11];
  const float* ln_b   = (const float*)d_in[12];
  float* out = (float*)d_out;

  char* ws = (char*)d_ws;
  float*  hjp     = (float*)ws;                        // 262144 B
  __bf16* w1t     = (__bf16*)(ws + 262144);            // 32768 B
  float*  cnt     = (float*)(ws + 262144 + 32768);     // 2048 B
  float*  partial = (float*)(ws + 262144 + 36864);     // 32*512*128*4 = 8 MiB

  k_pre<<<512, 128, 0, stream>>>(h, msg_w1, msg_b1, emask, w1t, hjp, cnt);
  k_main<<<1024, 256, 0, stream>>>(rel, emask, hjp, w1t, partial);
  k_update<<<512, 128, 0, stream>>>(h, partial, msg_w2, msg_b2, cnt,
                                    upd_w1, upd_b1, upd_w2, upd_b2,
                                    ln_g, ln_b, out);
}